// Round 7
// baseline (1003.640 us; speedup 1.0000x reference)
//
#include <hip/hip_runtime.h>
#include <hip/hip_bf16.h>

// RecNN: u = relu(contents @ W_u^T + b_u); v = u[internal] @ W_hu^T (hoisted);
// 10 levels emb = relu([emb_L|emb_R] @ W_LR^T + v + b_h).
//
// Round-7: register-direct GEMM (no LDS/barriers, r6) + OCCUPANCY FIX.
// r6 post-mortem: VGPR 116 + 64 acc-AGPR = 180 regs (unified file) -> only
// 2 waves/SIMD (Occupancy 21%); k-step time is memory-service-bound and
// hidden only by co-resident waves, so throughput ~ waves x prefetch-depth.
// Changes: __launch_bounds__(256,3) (cap 170 regs -> 3 waves/SIMD); fp32-A
// mode dropped (GEMM1 uses the bf16 linear path after a cvt pass); gathered
// mode runs as two k-halves (left rows then right rows) so only 4 A-pointers
// are live at a time (idx reloaded at the half switch, L2-hot).

typedef unsigned short u16;
typedef __attribute__((ext_vector_type(8))) short bf16x8;
typedef __attribute__((ext_vector_type(4))) float f32x4;

__device__ __forceinline__ u16 f2b(float f) {
  union { float f; unsigned u; } c; c.f = f;
  unsigned u = c.u;
  return (u16)((u + 0x7fffu + ((u >> 16) & 1u)) >> 16);  // RNE
}

__device__ __forceinline__ float b2f(unsigned hi16) {
  union { float f; unsigned u; } c; c.u = hi16 << 16; return c.f;
}

// EPI 0: bias+relu (GEMM1). EPI 1: +v+bias+relu, A gathered (levels).
// EPI 2: raw store (v-GEMM). A-source: EPI==1 -> gathered rows (stride 512,
// two halves via idx.x then idx.y); else linear [M][K] with K=kStride.
// M multiple of 64. Per-wave tile 64x64; block = 4 waves over 256 n-cols;
// 2 blocks per m-stripe cover N=512.
template <int EPI>
__global__ __launch_bounds__(256, 3)
void gemm_reg(const u16* __restrict__ A,
              const u16* __restrict__ embPrev,
              const int2* __restrict__ idx,
              const u16* __restrict__ vLvl,   // [M][512] bf16
              const u16* __restrict__ W,      // bf16, row stride ldb (B^T)
              int ldb,
              const float* __restrict__ bias,
              u16* __restrict__ out,          // [M][512] bf16
              int kStride, int halfK, int nHalf) {
  const int lane = threadIdx.x & 63;
  const int wv   = threadIdx.x >> 6;
  const int b    = blockIdx.x;
  const int m0   = (b >> 1) * 64;             // m-stripe shared by 2 blocks
  const int n0   = ((b & 1) * 4 + wv) * 64;   // per-wave n-slice
  const int fm   = lane & 15;
  const int kk   = (lane >> 4) * 8;

  const u16* brow[4];
#pragma unroll
  for (int j = 0; j < 4; j++)
    brow[j] = W + (size_t)(n0 + j * 16 + fm) * ldb + kk;

  f32x4 acc[4][4] = {};

  for (int h = 0; h < nHalf; h++) {
    // A row pointers for this half (4 frag rows: m0 + i*16 + fm).
    const u16* ap[4];
#pragma unroll
    for (int i = 0; i < 4; i++) {
      int m = m0 + i * 16 + fm;
      if (EPI == 1) {
        int2 c = idx[m];                      // reloaded per half (L2-hot)
        ap[i] = embPrev + (size_t)(h ? c.y : c.x) * 512 + kk;
      } else {
        ap[i] = A + (size_t)m * kStride + kk;
      }
    }
    const int bOff = h * halfK;

    bf16x8 a0[4], b0[4], a1[4], b1[4];
    auto loadA = [&](int k, bf16x8* a) {
#pragma unroll
      for (int i = 0; i < 4; i++) a[i] = *(const bf16x8*)(ap[i] + k);
    };
    auto loadB = [&](int k, bf16x8* bb) {
#pragma unroll
      for (int j = 0; j < 4; j++) bb[j] = *(const bf16x8*)(brow[j] + bOff + k);
    };
    auto mf = [&](bf16x8* a, bf16x8* bb) {
#pragma unroll
      for (int i = 0; i < 4; i++)
#pragma unroll
        for (int j = 0; j < 4; j++)
          acc[i][j] = __builtin_amdgcn_mfma_f32_16x16x32_bf16(a[i], bb[j], acc[i][j], 0, 0, 0);
    };

    loadA(0, a0); loadB(0, b0);
    for (int k = 0; k < halfK; k += 64) {
      if (k + 32 < halfK) { loadA(k + 32, a1); loadB(k + 32, b1); }
      mf(a0, b0);
      if (k + 64 < halfK) { loadA(k + 64, a0); loadB(k + 64, b0); }
      if (k + 32 < halfK) mf(a1, b1);
    }
  }

  // Epilogue: C/D layout col=lane&15, row=(lane>>4)*4+reg (m89-verified).
  const int r0 = (lane >> 4) * 4;
#pragma unroll
  for (int i = 0; i < 4; i++) {
    int mI = m0 + i * 16 + r0;
#pragma unroll
    for (int j = 0; j < 4; j++) {
      int col = n0 + j * 16 + fm;
      float bb = (EPI == 2) ? 0.f : bias[col];
#pragma unroll
      for (int r = 0; r < 4; r++) {
        int m = mI + r;
        float v = acc[i][j][r] + bb;
        if (EPI == 1) v += b2f(vLvl[(size_t)m * 512 + col]);
        if (EPI != 2) v = v > 0.f ? v : 0.f;
        out[(size_t)m * 512 + col] = f2b(v);
      }
    }
  }
}

// Generic fp32 -> bf16 stream (8 elems/thread).
__global__ void cvt_f32_to_bf16(const float* __restrict__ src, u16* __restrict__ dst, int n8) {
  int i = blockIdx.x * blockDim.x + threadIdx.x;
  if (i >= n8) return;
  const float4* s = (const float4*)src;
  float4 a = s[2 * i], b = s[2 * i + 1];
  union { __hip_bfloat162 h[4]; bf16x8 v; } o;
  o.h[0] = __float22bfloat162_rn({a.x, a.y});
  o.h[1] = __float22bfloat162_rn({a.z, a.w});
  o.h[2] = __float22bfloat162_rn({b.x, b.y});
  o.h[3] = __float22bfloat162_rn({b.z, b.w});
  *(bf16x8*)(dst + (size_t)i * 8) = o.v;
}

// One launch: convert W_u (512x256) and W_h (512x1536) fp32 -> bf16.
__global__ void cvt_weights(const float* __restrict__ Wu,
                            const float* __restrict__ Wh,
                            u16* __restrict__ Wub, u16* __restrict__ Whb) {
  const int nWu = 512 * 256 / 8;
  const int nWh = 512 * 1536 / 8;
  int i = blockIdx.x * blockDim.x + threadIdx.x;
  const float* src; u16* dst; int c;
  if (i < nWu) { src = Wu; dst = Wub; c = i; }
  else if (i < nWu + nWh) { src = Wh; dst = Whb; c = i - nWu; }
  else return;
  const float4* s = (const float4*)(src + (size_t)c * 8);
  float4 a = s[0], b = s[1];
  union { __hip_bfloat162 h[4]; bf16x8 v; } o;
  o.h[0] = __float22bfloat162_rn({a.x, a.y});
  o.h[1] = __float22bfloat162_rn({a.z, a.w});
  o.h[2] = __float22bfloat162_rn({b.x, b.y});
  o.h[3] = __float22bfloat162_rn({b.z, b.w});
  *(bf16x8*)(dst + (size_t)c * 8) = o.v;
}

__global__ void cvt_bf16_to_f32(const u16* __restrict__ src, float* __restrict__ dst, int n4) {
  int i = blockIdx.x * blockDim.x + threadIdx.x;
  if (i >= n4) return;
  uint2 p = ((const uint2*)src)[i];
  float4 o;
  o.x = b2f(p.x & 0xffffu); o.y = b2f(p.x >> 16);
  o.z = b2f(p.y & 0xffffu); o.w = b2f(p.y >> 16);
  ((float4*)dst)[i] = o;
}

extern "C" void kernel_launch(void* const* d_in, const int* in_sizes, int n_in,
                              void* d_out, int out_size, void* d_ws, size_t ws_size,
                              hipStream_t stream) {
  const float* contents = (const float*)d_in[0];
  const int2*  children = (const int2*)d_in[1];
  const float* W_u = (const float*)d_in[2];
  const float* b_u = (const float*)d_in[3];
  const float* W_h = (const float*)d_in[4];
  const float* b_h = (const float*)d_in[5];
  float* out = (float*)d_out;

  const int B = 64, D = 11, F = 256, H = 512;
  const int N = B * ((1 << D) - 1);            // 131008
  const int NI = B * ((1 << (D - 1)) - 1);     // 65472

  // Workspace (u16 elems): u_bf [N*512] | C [N*F] | Wub | Whb.
  // C holds contents_bf16 during GEMM1, then v (NI*512) after.
  // emb ping-pong aliases u's internal rows (dead after the v-GEMM).
  u16* ws16 = (u16*)d_ws;
  u16* u_bf = ws16;
  u16* C    = ws16 + (size_t)N * H;
  u16* Wub  = C + (size_t)N * F;
  u16* Whb  = Wub + 512 * 256;
  u16* cont_bf = C;
  u16* v_bf    = C;
  u16* embA = u_bf;                            // level-9 dst (32768 rows)
  u16* embB = u_bf + (size_t)32768 * 512;      // internal rows, dead

  // --- conversions ---
  {
    int n = (512 * 256 + 512 * 1536) / 8;
    cvt_weights<<<(n + 255) / 256, 256, 0, stream>>>(W_u, W_h, Wub, Whb);
    int n8 = N * F / 8;
    cvt_f32_to_bf16<<<(n8 + 255) / 256, 256, 0, stream>>>(contents, cont_bf, n8);
  }

  // --- GEMM1: u = relu(cont_bf @ W_u^T + b_u) ---
  gemm_reg<0><<<(N / 64) * 2, 256, 0, stream>>>(cont_bf, nullptr, nullptr,
                                                nullptr, Wub, F, b_u, u_bf,
                                                F, F, 1);

  // --- v-GEMM: v = u[0:NI] @ W_hu^T (W_h cols 1024..1535 in place) ---
  gemm_reg<2><<<(NI / 64) * 2, 256, 0, stream>>>(u_bf, nullptr, nullptr,
                                                 nullptr, Whb + 1024, 3 * H,
                                                 nullptr, v_bf, H, H, 1);

  // --- tree levels j = D-2 .. 0 (K=1024 in two gathered halves) ---
  const u16* embPrev = u_bf + (size_t)NI * H;  // leaves = u[NI:]
  u16* dst = embA;
  for (int j = D - 2; j >= 0; --j) {
    int M = B << j;
    int o = B * ((1 << j) - 1);
    gemm_reg<1><<<(M / 64) * 2, 256, 0, stream>>>(nullptr, embPrev, children + o,
                                                  v_bf + (size_t)o * H,
                                                  Whb, 3 * H, b_h, dst,
                                                  0, H, 2);
    embPrev = dst;
    dst = (dst == embA) ? embB : embA;
  }

  // --- level-0 emb (64 x 512) -> fp32 output ---
  {
    int n4 = B * H / 4;
    cvt_bf16_to_f32<<<(n4 + 255) / 256, 256, 0, stream>>>(embPrev, out, n4);
  }
}

// Round 8
// 745.626 us; speedup vs baseline: 1.3460x; 1.3460x over previous
//
#include <hip/hip_runtime.h>
#include <hip/hip_bf16.h>

// RecNN: u = relu(contents @ W_u^T + b_u); v = u[internal] @ W_hu^T (hoisted);
// 10 levels emb = relu([emb_L|emb_R] @ W_LR^T + v + b_h).
//
// Round-8: r4's 128x128/BK=32/4-wave LDS GEMM, but the k-loop is a 3-stage
// software pipeline with RAW s_barrier + manual s_waitcnt vmcnt(4)
// (m139/AITER recipe). Rounds 4-7 established the limiter is in-flight
// prefetch depth: with 1-deep prefetch + per-step vmcnt(0) drain, avg
// in-flight is only ~18 KB/CU -> ~20 B/cyc/CU staging rate -> 10% MfmaUtil.
// Here each wave issues exactly 4 glds per k-step and waits vmcnt(4) before
// the barrier, keeping the NEXT step's 16 KB/block permanently in flight
// (2 steps staged ahead, 3 LDS buffers). No other VMEM in the loop, so the
// count is exact. No __syncthreads anywhere in the k-loop.

typedef unsigned short u16;
typedef __attribute__((ext_vector_type(8))) short bf16x8;
typedef __attribute__((ext_vector_type(4))) float f32x4;

#define BK 32

__device__ __forceinline__ u16 f2b(float f) {
  union { float f; unsigned u; } c; c.f = f;
  unsigned u = c.u;
  return (u16)((u + 0x7fffu + ((u >> 16) & 1u)) >> 16);  // RNE
}

__device__ __forceinline__ float b2f(unsigned hi16) {
  union { float f; unsigned u; } c; c.u = hi16 << 16; return c.f;
}

__device__ __forceinline__ void glds16(const void* g, void* l) {
  __builtin_amdgcn_global_load_lds(
      (__attribute__((address_space(1))) void*)g,
      (__attribute__((address_space(3))) void*)l, 16, 0, 0);
}

// s_waitcnt with only vmcnt active: lgkmcnt=15, expcnt=7.
// imm = (lgkm<<8)|(exp<<4)|vmcnt_lo  (vmcnt<=15 here)
#define WAITV4() __builtin_amdgcn_s_waitcnt(0x0F74)
#define WAITV0() __builtin_amdgcn_s_waitcnt(0x0F70)
#define BAR()    __builtin_amdgcn_s_barrier()

// EPI 0: bias+relu (GEMM1, A bf16 linear). EPI 1: gathered A + v+bias+relu
// (levels). EPI 2: raw store (v-GEMM, A bf16 linear).
template <int EPI>
__global__ __launch_bounds__(256)
void gemm_p3(const u16* __restrict__ A,
             const u16* __restrict__ embPrev,
             const int2* __restrict__ idx,
             const u16* __restrict__ vLvl,   // [M][512] bf16
             const u16* __restrict__ W,      // bf16, row stride ldb (B^T)
             int ldb,
             const float* __restrict__ bias,
             u16* __restrict__ out,          // [M][512] bf16
             int M, int K, int nBlkM) {
  __shared__ __align__(16) u16 lA[3][128 * BK];   // 3 x 8 KB
  __shared__ __align__(16) u16 lB[3][128 * BK];   // 3 x 8 KB

  const int tid  = threadIdx.x;
  const int lane = tid & 63;
  const int wv   = tid >> 6;
  const int wrow = wv >> 1, wcol = wv & 1;

  // XCD swizzle: the 4 n-blocks of one m-block land on the same XCD and are
  // dispatch-adjacent, so A-tile re-reads hit that XCD's L2.
  int mb, nb;
  {
    int b = blockIdx.x;
    if ((nBlkM & 7) == 0) {
      int xcd = b & 7;
      nb = (b >> 3) & 3;
      mb = ((b >> 5) << 3) | xcd;
    } else { nb = b & 3; mb = b >> 2; }
  }
  const int mBase = mb * 128;
  const int n0    = nb * 128;

  const int rowA0 = tid >> 2;       // 0..63 (round 0; +64 round 1)
  const int q     = tid & 3;
  const int colq  = q * 8;

  const u16 *ab0 = nullptr, *ab1 = nullptr;
  const u16 *aL0 = nullptr, *aR0 = nullptr, *aL1 = nullptr, *aR1 = nullptr;
  {
    int m0 = min(mBase + rowA0, M - 1);
    int m1 = min(mBase + rowA0 + 64, M - 1);
    if (EPI == 1) {
      int2 c0 = idx[m0], c1 = idx[m1];
      aL0 = embPrev + (size_t)c0.x * 512 + colq;
      aR0 = embPrev + (size_t)c0.y * 512 + colq;
      aL1 = embPrev + (size_t)c1.x * 512 + colq;
      aR1 = embPrev + (size_t)c1.y * 512 + colq;
    } else {
      ab0 = A + (size_t)m0 * K + colq;
      ab1 = A + (size_t)m1 * K + colq;
    }
  }
  const u16* bp0 = W + (size_t)(n0 + rowA0) * ldb + colq;
  const u16* bp1 = W + (size_t)(n0 + rowA0 + 64) * ldb + colq;

  f32x4 acc[4][4] = {};
  const int fm = lane & 15;
  const int kk = (lane >> 4) * 8;
  const int nk = K / BK;

  // Exactly 4 glds per thread per step (vmcnt bookkeeping depends on it).
  auto stage = [&](int buf, int k0) {
    if (EPI == 1) {
      const u16* g0 = ((k0 & 512) ? aR0 : aL0) + (k0 & 511);
      const u16* g1 = ((k0 & 512) ? aR1 : aL1) + (k0 & 511);
      glds16(g0, &lA[buf][tid * 8]);
      glds16(g1, &lA[buf][(tid + 256) * 8]);
    } else {
      glds16(ab0 + k0, &lA[buf][tid * 8]);
      glds16(ab1 + k0, &lA[buf][(tid + 256) * 8]);
    }
    glds16(bp0 + k0, &lB[buf][tid * 8]);
    glds16(bp1 + k0, &lB[buf][(tid + 256) * 8]);
  };

  // Prologue: 2 steps staged ahead.
  stage(0, 0);
  stage(1, BK);

  int buf = 0;
  for (int ks = 0; ks < nk; ks++) {
    if (ks + 2 < nk) {
      WAITV4();                      // step ks landed; step ks+1 stays in flight
      BAR();
      int nxt = buf + 2; if (nxt >= 3) nxt -= 3;
      stage(nxt, (ks + 2) * BK);     // overlaps the MFMA stage below
    } else if (ks + 1 < nk) {
      WAITV4();
      BAR();
    } else {
      WAITV0();
      BAR();
    }

    bf16x8 av[4], bv[4];
#pragma unroll
    for (int i = 0; i < 4; i++) {
      av[i] = *(const bf16x8*)&lA[buf][(wrow * 64 + i * 16 + fm) * BK + kk];
      bv[i] = *(const bf16x8*)&lB[buf][(wcol * 64 + i * 16 + fm) * BK + kk];
    }
#pragma unroll
    for (int i = 0; i < 4; i++)
#pragma unroll
      for (int j = 0; j < 4; j++)
        acc[i][j] = __builtin_amdgcn_mfma_f32_16x16x32_bf16(av[i], bv[j], acc[i][j], 0, 0, 0);

    buf++; if (buf == 3) buf = 0;
  }

  // Epilogue: C/D layout col=lane&15, row=(lane>>4)*4+reg (m89-verified).
  const int r0 = (lane >> 4) * 4;
#pragma unroll
  for (int i = 0; i < 4; i++) {
    int mI = mBase + wrow * 64 + i * 16 + r0;
#pragma unroll
    for (int j = 0; j < 4; j++) {
      int col = n0 + wcol * 64 + j * 16 + fm;
      float bb = (EPI == 2) ? 0.f : bias[col];
#pragma unroll
      for (int r = 0; r < 4; r++) {
        int m = mI + r;
        if (m < M) {
          float v = acc[i][j][r] + bb;
          if (EPI == 1) v += b2f(vLvl[(size_t)m * 512 + col]);
          if (EPI != 2) v = v > 0.f ? v : 0.f;
          out[(size_t)m * 512 + col] = f2b(v);
        }
      }
    }
  }
}

// Generic fp32 -> bf16 stream (8 elems/thread).
__global__ void cvt_f32_to_bf16(const float* __restrict__ src, u16* __restrict__ dst, int n8) {
  int i = blockIdx.x * blockDim.x + threadIdx.x;
  if (i >= n8) return;
  const float4* s = (const float4*)src;
  float4 a = s[2 * i], b = s[2 * i + 1];
  union { __hip_bfloat162 h[4]; bf16x8 v; } o;
  o.h[0] = __float22bfloat162_rn({a.x, a.y});
  o.h[1] = __float22bfloat162_rn({a.z, a.w});
  o.h[2] = __float22bfloat162_rn({b.x, b.y});
  o.h[3] = __float22bfloat162_rn({b.z, b.w});
  *(bf16x8*)(dst + (size_t)i * 8) = o.v;
}

// One launch: convert W_u (512x256) and W_h (512x1536) fp32 -> bf16.
__global__ void cvt_weights(const float* __restrict__ Wu,
                            const float* __restrict__ Wh,
                            u16* __restrict__ Wub, u16* __restrict__ Whb) {
  const int nWu = 512 * 256 / 8;
  const int nWh = 512 * 1536 / 8;
  int i = blockIdx.x * blockDim.x + threadIdx.x;
  const float* src; u16* dst; int c;
  if (i < nWu) { src = Wu; dst = Wub; c = i; }
  else if (i < nWu + nWh) { src = Wh; dst = Whb; c = i - nWu; }
  else return;
  const float4* s = (const float4*)(src + (size_t)c * 8);
  float4 a = s[0], b = s[1];
  union { __hip_bfloat162 h[4]; bf16x8 v; } o;
  o.h[0] = __float22bfloat162_rn({a.x, a.y});
  o.h[1] = __float22bfloat162_rn({a.z, a.w});
  o.h[2] = __float22bfloat162_rn({b.x, b.y});
  o.h[3] = __float22bfloat162_rn({b.z, b.w});
  *(bf16x8*)(dst + (size_t)c * 8) = o.v;
}

__global__ void cvt_bf16_to_f32(const u16* __restrict__ src, float* __restrict__ dst, int n4) {
  int i = blockIdx.x * blockDim.x + threadIdx.x;
  if (i >= n4) return;
  uint2 p = ((const uint2*)src)[i];
  float4 o;
  o.x = b2f(p.x & 0xffffu); o.y = b2f(p.x >> 16);
  o.z = b2f(p.y & 0xffffu); o.w = b2f(p.y >> 16);
  ((float4*)dst)[i] = o;
}

extern "C" void kernel_launch(void* const* d_in, const int* in_sizes, int n_in,
                              void* d_out, int out_size, void* d_ws, size_t ws_size,
                              hipStream_t stream) {
  const float* contents = (const float*)d_in[0];
  const int2*  children = (const int2*)d_in[1];
  const float* W_u = (const float*)d_in[2];
  const float* b_u = (const float*)d_in[3];
  const float* W_h = (const float*)d_in[4];
  const float* b_h = (const float*)d_in[5];
  float* out = (float*)d_out;

  const int B = 64, D = 11, F = 256, H = 512;
  const int N = B * ((1 << D) - 1);            // 131008
  const int NI = B * ((1 << (D - 1)) - 1);     // 65472

  // Workspace (u16 elems): u_bf [N*512] | C [N*F] | Wub | Whb.
  // C = contents_bf16 during GEMM1, then v (NI*512 <= N*F) after.
  // emb ping-pong aliases u's internal rows (dead after the v-GEMM).
  u16* ws16 = (u16*)d_ws;
  u16* u_bf = ws16;
  u16* C    = ws16 + (size_t)N * H;
  u16* Wub  = C + (size_t)N * F;
  u16* Whb  = Wub + 512 * 256;
  u16* cont_bf = C;
  u16* v_bf    = C;
  u16* embA = u_bf;                            // level-9 dst (32768 rows)
  u16* embB = u_bf + (size_t)32768 * 512;      // internal rows, dead

  // --- conversions ---
  {
    int n = (512 * 256 + 512 * 1536) / 8;
    cvt_weights<<<(n + 255) / 256, 256, 0, stream>>>(W_u, W_h, Wub, Whb);
    int n8 = N * F / 8;
    cvt_f32_to_bf16<<<(n8 + 255) / 256, 256, 0, stream>>>(contents, cont_bf, n8);
  }

  // --- GEMM1: u = relu(cont_bf @ W_u^T + b_u) ---
  {
    int mb = (N + 127) / 128;                  // 1024
    gemm_p3<0><<<mb * 4, 256, 0, stream>>>(cont_bf, nullptr, nullptr, nullptr,
                                           Wub, F, b_u, u_bf, N, F, mb);
  }

  // --- v-GEMM: v = u[0:NI] @ W_hu^T (W_h cols 1024..1535 in place) ---
  {
    int mb = (NI + 127) / 128;                 // 512
    gemm_p3<2><<<mb * 4, 256, 0, stream>>>(u_bf, nullptr, nullptr, nullptr,
                                           Whb + 1024, 3 * H, nullptr,
                                           v_bf, NI, H, mb);
  }

  // --- tree levels j = D-2 .. 0 (K=1024 children; v in epilogue) ---
  const u16* embPrev = u_bf + (size_t)NI * H;  // leaves = u[NI:]
  u16* dst = embA;
  for (int j = D - 2; j >= 0; --j) {
    int M = B << j;
    int o = B * ((1 << j) - 1);
    int mb = (M + 127) / 128;
    gemm_p3<1><<<mb * 4, 256, 0, stream>>>(nullptr, embPrev, children + o,
                                           v_bf + (size_t)o * H,
                                           Whb, 3 * H, b_h, dst, M, 2 * H, mb);
    embPrev = dst;
    dst = (dst == embA) ? embB : embA;
  }

  // --- level-0 emb (64 x 512) -> fp32 output ---
  {
    int n4 = B * H / 4;
    cvt_bf16_to_f32<<<(n4 + 255) / 256, 256, 0, stream>>>(embPrev, out, n4);
  }
}